// Round 1
// baseline (5540.183 us; speedup 1.0000x reference)
//
#include <hip/hip_runtime.h>
#include <stdint.h>

// Problem constants: B=64, T=512, I=256, H=512, L=2
#define Bn 64
#define Tn 512
#define In 256
#define Hn 512
#define NBLK 64                    // 32 blocks layer0 + 32 blocks layer1
#define OUT_HT 16777216            // B*T*H  (start of hT)
#define OUT_CT 16842752            // OUT_HT + 2*B*H (start of cT)
#define SLOT_ELEMS (Bn * Hn)       // 32768 bf16 = 64KB per h slot

// ---------------------------------------------------------------------------
// v2 design: weights persist in the REGISTER FILE (VGPR+AGPR), not LDS.
//   - 4 waves/block remapped from 4 row-tiles to (row-half r) x (K-half kw).
//   - Each wave holds its B-slice as 64 bf16x8 frags = 256 regs (loop-invariant,
//     loaded+converted once). At 1 wave/SIMD the unified 512-reg file fits this.
//   - Eliminates ~512 KB/CU/step of ds_read_b128 (the former dominant term).
//   - K-halves exchange 16 f32/lane partials via 32KB LDS ping-pong,
//     ONE __syncthreads per step; each wave epilogues its own 16-row tile.
//   - Flags: flag[layer][block][rowtile(0..3)] = step done. Consumers poll
//     exactly 64 words (one per lane) with s_sleep backoff.
//   - Ring guard: only L0 needs an explicit guard (L1's h0-reads), on the
//     kw0-rows flags of flag1; everything else implied by barrier+spin order.
// ---------------------------------------------------------------------------

typedef __attribute__((ext_vector_type(8))) short bf16x8;
typedef __attribute__((ext_vector_type(4))) float f32x4;
typedef unsigned long long u64;

__device__ __forceinline__ unsigned short f2bf(float f) {   // fp32 -> bf16 RNE
    unsigned u = __float_as_uint(f);
    return (unsigned short)((u + 0x7fffu + ((u >> 16) & 1u)) >> 16);
}
__device__ __forceinline__ float sigm(float v) { return 1.0f / (1.0f + __expf(-v)); }
__device__ __forceinline__ float tanhv(float v) { float e = __expf(2.0f * v); return 1.0f - 2.0f / (e + 1.0f); }

// sc0/sc1 accesses: bypass per-XCD L1/L2, coherent at Infinity Cache (L3).
__device__ __forceinline__ void stg_coh(unsigned short* p, unsigned short v) {
    __hip_atomic_store(p, v, __ATOMIC_RELAXED, __HIP_MEMORY_SCOPE_AGENT);
}
__device__ __forceinline__ int ld_flag(const int* p) {
    return __hip_atomic_load(p, __ATOMIC_RELAXED, __HIP_MEMORY_SCOPE_AGENT);
}
__device__ __forceinline__ void st_flag(int* p, int v) {
    __hip_atomic_store(p, v, __ATOMIC_RELAXED, __HIP_MEMORY_SCOPE_AGENT);
}
__device__ __forceinline__ bf16x8 asbf(f32x4 v) {
    union { f32x4 f; bf16x8 h; } u; u.f = v; return u.h;
}

// Batched sc1 frag loads: all issued back-to-back, ONE waitcnt. Forces a
// single L3 round-trip regardless of compiler register heuristics.
#define GLD32(A, B, VA, VB)                                            \
  asm volatile(                                                        \
    "global_load_dwordx4 %0,  %32, off offset:0 sc0 sc1\n\t"          \
    "global_load_dwordx4 %1,  %32, off offset:64 sc0 sc1\n\t"         \
    "global_load_dwordx4 %2,  %32, off offset:128 sc0 sc1\n\t"        \
    "global_load_dwordx4 %3,  %32, off offset:192 sc0 sc1\n\t"        \
    "global_load_dwordx4 %4,  %32, off offset:256 sc0 sc1\n\t"        \
    "global_load_dwordx4 %5,  %32, off offset:320 sc0 sc1\n\t"        \
    "global_load_dwordx4 %6,  %32, off offset:384 sc0 sc1\n\t"        \
    "global_load_dwordx4 %7,  %32, off offset:448 sc0 sc1\n\t"        \
    "global_load_dwordx4 %8,  %32, off offset:512 sc0 sc1\n\t"        \
    "global_load_dwordx4 %9,  %32, off offset:576 sc0 sc1\n\t"        \
    "global_load_dwordx4 %10, %32, off offset:640 sc0 sc1\n\t"        \
    "global_load_dwordx4 %11, %32, off offset:704 sc0 sc1\n\t"        \
    "global_load_dwordx4 %12, %32, off offset:768 sc0 sc1\n\t"        \
    "global_load_dwordx4 %13, %32, off offset:832 sc0 sc1\n\t"        \
    "global_load_dwordx4 %14, %32, off offset:896 sc0 sc1\n\t"        \
    "global_load_dwordx4 %15, %32, off offset:960 sc0 sc1\n\t"        \
    "global_load_dwordx4 %16, %33, off offset:0 sc0 sc1\n\t"          \
    "global_load_dwordx4 %17, %33, off offset:64 sc0 sc1\n\t"         \
    "global_load_dwordx4 %18, %33, off offset:128 sc0 sc1\n\t"        \
    "global_load_dwordx4 %19, %33, off offset:192 sc0 sc1\n\t"        \
    "global_load_dwordx4 %20, %33, off offset:256 sc0 sc1\n\t"        \
    "global_load_dwordx4 %21, %33, off offset:320 sc0 sc1\n\t"        \
    "global_load_dwordx4 %22, %33, off offset:384 sc0 sc1\n\t"        \
    "global_load_dwordx4 %23, %33, off offset:448 sc0 sc1\n\t"        \
    "global_load_dwordx4 %24, %33, off offset:512 sc0 sc1\n\t"        \
    "global_load_dwordx4 %25, %33, off offset:576 sc0 sc1\n\t"        \
    "global_load_dwordx4 %26, %33, off offset:640 sc0 sc1\n\t"        \
    "global_load_dwordx4 %27, %33, off offset:704 sc0 sc1\n\t"        \
    "global_load_dwordx4 %28, %33, off offset:768 sc0 sc1\n\t"        \
    "global_load_dwordx4 %29, %33, off offset:832 sc0 sc1\n\t"        \
    "global_load_dwordx4 %30, %33, off offset:896 sc0 sc1\n\t"        \
    "global_load_dwordx4 %31, %33, off offset:960 sc0 sc1\n\t"        \
    "s_waitcnt vmcnt(0)"                                               \
    : "=&v"(A[0]), "=&v"(A[1]), "=&v"(A[2]), "=&v"(A[3]),              \
      "=&v"(A[4]), "=&v"(A[5]), "=&v"(A[6]), "=&v"(A[7]),              \
      "=&v"(A[8]), "=&v"(A[9]), "=&v"(A[10]), "=&v"(A[11]),            \
      "=&v"(A[12]), "=&v"(A[13]), "=&v"(A[14]), "=&v"(A[15]),          \
      "=&v"(B[0]), "=&v"(B[1]), "=&v"(B[2]), "=&v"(B[3]),              \
      "=&v"(B[4]), "=&v"(B[5]), "=&v"(B[6]), "=&v"(B[7]),              \
      "=&v"(B[8]), "=&v"(B[9]), "=&v"(B[10]), "=&v"(B[11]),            \
      "=&v"(B[12]), "=&v"(B[13]), "=&v"(B[14]), "=&v"(B[15])           \
    : "v"(VA), "v"(VB) : "memory")

__global__ void lstm_prep(u64* __restrict__ z0, u64* __restrict__ z1,
                          int* __restrict__ fl) {
    int tid = blockIdx.x * blockDim.x + threadIdx.x;
    if (tid < 256) st_flag(fl + tid, 0);
    // zero slot 0 of both h rings (h(-1) = 0) with sc1 stores -> land in L3
    for (int i = tid; i < SLOT_ELEMS / 4; i += gridDim.x * blockDim.x) {
        __hip_atomic_store(z0 + i, (u64)0, __ATOMIC_RELAXED, __HIP_MEMORY_SCOPE_AGENT);
        __hip_atomic_store(z1 + i, (u64)0, __ATOMIC_RELAXED, __HIP_MEMORY_SCOPE_AGENT);
    }
}

__launch_bounds__(256, 1)
__global__ void lstm_main(const float* __restrict__ x,
                          const float* __restrict__ wxh0, const float* __restrict__ whh0,
                          const float* __restrict__ wxh1, const float* __restrict__ whh1,
                          const float* __restrict__ bx0, const float* __restrict__ bh0,
                          const float* __restrict__ bx1, const float* __restrict__ bh1,
                          float* __restrict__ out,
                          unsigned short* __restrict__ h0b,
                          unsigned short* __restrict__ h1b,
                          int* __restrict__ flags, int nslot) {
    __shared__ f32x4 pbuf[2][16][64];         // [parity][(r*2+srt)*4+q][lane] : 32KB

    const int layer = blockIdx.x >> 5;        // 0 or 1
    const int cb    = blockIdx.x & 31;        // owns h cols [cb*16, cb*16+16)
    const int wv    = threadIdx.x >> 6;
    const int lane  = threadIdx.x & 63;
    const int kw    = wv & 1;                 // K-half (L0: kw0=x-part, kw1=h-part)
    const int r     = wv >> 1;                // row half: rows [r*32, r*32+32)
    const int quad  = lane >> 4;
    const int ln    = lane & 15;
    const int colh  = (cb << 4) + ln;
    const int row0  = r << 5;

    // ---- role: weight source for this wave's K-slice ----
    const float* Wsrc; int Kd, NI;
    const float *bxp, *bhp;
    if (layer == 0) {
        bxp = bx0; bhp = bh0;
        if (kw == 0) { Wsrc = wxh0; Kd = In; NI = 8;  }   // x side, K=256
        else         { Wsrc = whh0; Kd = Hn; NI = 16; }   // h0(t-1) side, K=512
    } else {
        bxp = bx1; bhp = bh1;
        if (kw == 0) { Wsrc = wxh1; Kd = Hn; NI = 16; }   // h0(t) side
        else         { Wsrc = whh1; Kd = Hn; NI = 16; }   // h1(t-1) side
    }

    // ---- load B-frags once: fp32 -> bf16, persist in registers (AGPR/VGPR) ----
    // frag (i,q), lane l: W[q*512 + cb*16 + (l&15)][i*32 + (l>>4)*8 + 0..7]
    bf16x8 wB[64];
#pragma unroll
    for (int i = 0; i < 16; ++i) {
        if (i < NI) {
#pragma unroll
            for (int q = 0; q < 4; ++q) {
                const float* src = Wsrc + (size_t)(q * Hn + colh) * Kd + i * 32 + quad * 8;
                f32x4 s0 = *(const f32x4*)src;
                f32x4 s1 = *(const f32x4*)(src + 4);
                bf16x8 w;
                w[0] = (short)f2bf(s0[0]); w[1] = (short)f2bf(s0[1]);
                w[2] = (short)f2bf(s0[2]); w[3] = (short)f2bf(s0[3]);
                w[4] = (short)f2bf(s1[0]); w[5] = (short)f2bf(s1[1]);
                w[6] = (short)f2bf(s1[2]); w[7] = (short)f2bf(s1[3]);
                wB[i * 4 + q] = w;
            }
        }
    }

    float bias[4];
#pragma unroll
    for (int q = 0; q < 4; ++q) bias[q] = bxp[q * Hn + colh] + bhp[q * Hn + colh];

    // ---- flag topology: flag[L][b][rg] at flags[L*128 + b*4 + rg], rg = r*2 + kw
    // (wave (r,kw) epilogues rows r*32+kw*16 .. +16 and publishes rg = r*2+kw).
    // Consumers read 32-row groups -> watch rg in {2r, 2r+1} of 32 blocks = 64 flags.
    const int* spin_fp;
    int dt = 0;
    if (layer == 0 && kw == 0) {
        // ring guard only: L1's h0-readers (kw0 waves, rg in {0,2}) of all blocks
        spin_fp = flags + 128 + (lane >> 1) * 4 + (lane & 1) * 2;
    } else if (layer == 0) {          // kw1: h0(t-1), needs flag0 >= t
        spin_fp = flags + (lane >> 1) * 4 + 2 * r + (lane & 1); dt = 0;
    } else if (kw == 0) {             // L1: h0(t), needs flag0 >= t+1
        spin_fp = flags + (lane >> 1) * 4 + 2 * r + (lane & 1); dt = 1;
    } else {                          // L1: h1(t-1), needs flag1 >= t
        spin_fp = flags + 128 + (lane >> 1) * 4 + 2 * r + (lane & 1); dt = 0;
    }
    int* pub_fp = flags + layer * 128 + cb * 4 + r * 2 + kw;

    float cst[4] = {0.f, 0.f, 0.f, 0.f};     // c-state for this wave's 16 rows
    int rs = 0, wsl = 1;

    for (int t = 0; t < Tn; ++t) {
        const int par = t & 1;
        f32x4 acc0[4], acc1[4];               // rt0 = rows row0..+16, rt1 = +16..+32
        if (kw == 0) {                        // bias goes into the KEPT half only
#pragma unroll
            for (int q = 0; q < 4; ++q) {
                acc0[q] = (f32x4){bias[q], bias[q], bias[q], bias[q]};
                acc1[q] = (f32x4){0.f, 0.f, 0.f, 0.f};
            }
        } else {
#pragma unroll
            for (int q = 0; q < 4; ++q) {
                acc0[q] = (f32x4){0.f, 0.f, 0.f, 0.f};
                acc1[q] = (f32x4){bias[q], bias[q], bias[q], bias[q]};
            }
        }

        if (layer == 0 && kw == 0) {
            // ---- x-part: no data dependence -> compute BEFORE any spin ----
            const float* xp0 = x + (size_t)(row0 + ln) * (Tn * In) + (size_t)t * In + quad * 8;
            const float* xp1 = xp0 + (size_t)16 * (Tn * In);
            f32x4 xr[32];
#pragma unroll
            for (int i = 0; i < 8; ++i) {
                xr[2 * i]        = *(const f32x4*)(xp0 + i * 32);
                xr[2 * i + 1]    = *(const f32x4*)(xp0 + i * 32 + 4);
                xr[16 + 2 * i]   = *(const f32x4*)(xp1 + i * 32);
                xr[16 + 2 * i + 1] = *(const f32x4*)(xp1 + i * 32 + 4);
            }
            bf16x8 a0[8], a1[8];
#pragma unroll
            for (int i = 0; i < 8; ++i) {
                f32x4 xa = xr[2 * i], xc = xr[2 * i + 1];
                a0[i][0] = (short)f2bf(xa[0]); a0[i][1] = (short)f2bf(xa[1]);
                a0[i][2] = (short)f2bf(xa[2]); a0[i][3] = (short)f2bf(xa[3]);
                a0[i][4] = (short)f2bf(xc[0]); a0[i][5] = (short)f2bf(xc[1]);
                a0[i][6] = (short)f2bf(xc[2]); a0[i][7] = (short)f2bf(xc[3]);
                f32x4 xb = xr[16 + 2 * i], xd = xr[16 + 2 * i + 1];
                a1[i][0] = (short)f2bf(xb[0]); a1[i][1] = (short)f2bf(xb[1]);
                a1[i][2] = (short)f2bf(xb[2]); a1[i][3] = (short)f2bf(xb[3]);
                a1[i][4] = (short)f2bf(xd[0]); a1[i][5] = (short)f2bf(xd[1]);
                a1[i][6] = (short)f2bf(xd[2]); a1[i][7] = (short)f2bf(xd[3]);
            }
#pragma unroll
            for (int i = 0; i < 8; ++i)
#pragma unroll
                for (int q = 0; q < 4; ++q)
                    acc0[q] = __builtin_amdgcn_mfma_f32_16x16x32_bf16(a0[i], wB[i * 4 + q], acc0[q], 0, 0, 0);
#pragma unroll
            for (int i = 0; i < 8; ++i)
#pragma unroll
                for (int q = 0; q < 4; ++q)
                    acc1[q] = __builtin_amdgcn_mfma_f32_16x16x32_bf16(a1[i], wB[i * 4 + q], acc1[q], 0, 0, 0);
            // ring-reuse guard (protects the whole block's h0 stores; kw1
            // inherits it through the barrier below). Skipped while slack.
            int tgt = t + 2 - nslot;
            if (tgt > 0) {
                int v = ld_flag(spin_fp);
                while (!__all(v >= tgt)) { __builtin_amdgcn_s_sleep(1); v = ld_flag(spin_fp); }
            }
        } else {
            // ---- h-part: spin, then one batched L3 round-trip, then MFMA ----
            int tgt = t + dt;
            int v = ld_flag(spin_fp);
            while (!__all(v >= tgt)) { __builtin_amdgcn_s_sleep(1); v = ld_flag(spin_fp); }
            asm volatile("" ::: "memory");    // no load hoisting above the spin
            const unsigned short* ring = (layer == 0) ? h0b : ((kw == 0) ? h0b : h1b);
            const int slot = (layer == 1 && kw == 0) ? wsl : rs;
            const unsigned short* hp = ring + (size_t)slot * SLOT_ELEMS
                                     + (size_t)(row0 + ln) * Hn + quad * 8;
            uint64_t va = (uint64_t)hp, vb = va + (size_t)(16 * Hn * 2);
            f32x4 A[16], Bv[16];
            GLD32(A, Bv, va, vb);
#pragma unroll
            for (int i = 0; i < 16; ++i)
#pragma unroll
                for (int q = 0; q < 4; ++q)
                    acc0[q] = __builtin_amdgcn_mfma_f32_16x16x32_bf16(asbf(A[i]), wB[i * 4 + q], acc0[q], 0, 0, 0);
#pragma unroll
            for (int i = 0; i < 16; ++i)
#pragma unroll
                for (int q = 0; q < 4; ++q)
                    acc1[q] = __builtin_amdgcn_mfma_f32_16x16x32_bf16(asbf(Bv[i]), wB[i * 4 + q], acc1[q], 0, 0, 0);
        }

        // ---- cross-K exchange: send the non-owned row half, keep the other ----
        if (kw == 0) {
#pragma unroll
            for (int q = 0; q < 4; ++q) pbuf[par][(r * 2 + 1) * 4 + q][lane] = acc1[q];
        } else {
#pragma unroll
            for (int q = 0; q < 4; ++q) pbuf[par][(r * 2 + 0) * 4 + q][lane] = acc0[q];
        }
        __syncthreads();                      // the ONLY block-wide sync per step
        f32x4 mine[4];
        if (kw == 0) {
#pragma unroll
            for (int q = 0; q < 4; ++q) mine[q] = acc0[q] + pbuf[par][(r * 2 + 0) * 4 + q][lane];
        } else {
#pragma unroll
            for (int q = 0; q < 4; ++q) mine[q] = acc1[q] + pbuf[par][(r * 2 + 1) * 4 + q][lane];
        }

        // ---- LSTM cell epilogue for this wave's 16-row tile; sc1 h stores ----
        unsigned short* hw = ((layer == 0) ? h0b : h1b) + (size_t)wsl * SLOT_ELEMS;
        const int rowb = row0 + (kw << 4) + (quad << 2);
#pragma unroll
        for (int j = 0; j < 4; ++j) {
            const int row = rowb + j;
            float ig = sigm(mine[0][j]);
            float fg = sigm(mine[1][j]);
            float gg = tanhv(mine[2][j]);
            float og = sigm(mine[3][j]);
            float cy = cst[j] * fg + ig * gg;
            float hy = og * tanhv(cy);
            cst[j] = cy;
            stg_coh(hw + row * Hn + colh, f2bf(hy));
            if (layer == 1) out[(size_t)row * (Tn * Hn) + (size_t)t * Hn + colh] = hy;
            if (t == Tn - 1) {
                out[OUT_HT + layer * (Bn * Hn) + row * Hn + colh] = hy;
                out[OUT_CT + layer * (Bn * Hn) + row * Hn + colh] = cy;
            }
        }

        // publish: own stores at L3 (vmcnt drain), then flag — per wave
        asm volatile("s_waitcnt vmcnt(0)" ::: "memory");
        if (lane == 0) st_flag(pub_fp, t + 1);

        rs = wsl;
        wsl = (wsl + 1 == nslot) ? 0 : wsl + 1;
    }
}

extern "C" void kernel_launch(void* const* d_in, const int* in_sizes, int n_in,
                              void* d_out, int out_size, void* d_ws, size_t ws_size,
                              hipStream_t stream) {
    const float* x    = (const float*)d_in[0];
    const float* wxh0 = (const float*)d_in[1];
    const float* bxh0 = (const float*)d_in[2];
    const float* whh0 = (const float*)d_in[3];
    const float* bhh0 = (const float*)d_in[4];
    const float* wxh1 = (const float*)d_in[5];
    const float* bxh1 = (const float*)d_in[6];
    const float* whh1 = (const float*)d_in[7];
    const float* bhh1 = (const float*)d_in[8];
    float* out = (float*)d_out;

    char* ws = (char*)d_ws;
    int* flags = (int*)ws;
    long nslot_l = (long)((ws_size - 4096) / (2 * (size_t)SLOT_ELEMS * 2));
    int nslot = (int)(nslot_l < 3 ? 3 : (nslot_l > Tn + 1 ? Tn + 1 : nslot_l));
    unsigned short* h0b = (unsigned short*)(ws + 4096);
    unsigned short* h1b = h0b + (size_t)nslot * SLOT_ELEMS;

    lstm_prep<<<dim3(32), dim3(256), 0, stream>>>((u64*)h0b, (u64*)h1b, flags);

    lstm_main<<<dim3(NBLK), dim3(256), 0, stream>>>(
        x, wxh0, whh0, wxh1, whh1, bxh0, bhh0, bxh1, bhh1,
        out, h0b, h1b, flags, nslot);
}

// Round 2
// 4915.471 us; speedup vs baseline: 1.1271x; 1.1271x over previous
//
#include <hip/hip_runtime.h>
#include <stdint.h>

// Problem constants: B=64, T=512, I=256, H=512, L=2
#define Bn 64
#define Tn 512
#define In 256
#define Hn 512
#define NBLK 64                    // 32 blocks layer0 + 32 blocks layer1
#define OUT_HT 16777216            // B*T*H  (start of hT)
#define OUT_CT 16842752            // OUT_HT + 2*B*H (start of cT)
#define SLOTU 32768                // u32 elems per h slot (64 rows x 512 feats)
#define NS1 8                      // h1 ring slots (intra-L1 skew <= 1)
#define NS0MAX 64                  // h0 ring slots (L0->L1 elasticity)
#define PD 4                       // LDS feed-partial ring depth
#define LDS_BYTES 65600            // PD*2*8*64*16 + flags

// ---------------------------------------------------------------------------
// v3: latency-first design.
//  * h ring elements are TAGGED u32 = (step<<16)|bf16.  Consumers validate
//    readiness from the data itself -> no producer vmcnt drain, no flag store,
//    no flag-poll hop.  Producer h-stores are fire-and-forget.
//  * Wave specialization, NO per-step __syncthreads:
//      wv 0,1 = FEED  (r=0,1): x@Wx (L0) or h0(t)@Wx1 (L1); runs AHEAD,
//               hands f32 partials to rec via 4-deep LDS ring (pair flags).
//      wv 2,3 = REC   (r=0,1): h(t-1)@Wh for rows [r*32,r*32+32), full K=512,
//               weights in 256 register-resident frags; owns epilogue+stores.
//  * Sentinel spin: 4B/lane covering one word from each producer block, then
//    one batched 32x16B load per rowtile with full tag verification (retry).
//  * Guards: only L0-rec vs L1-feed ring reuse (flags[0..63]), batched so it
//    polls ~once per 48 steps.  All other reuse is bounded by lockstep skew.
// ---------------------------------------------------------------------------

typedef __attribute__((ext_vector_type(8))) short bf16x8;
typedef __attribute__((ext_vector_type(4))) float f32x4;
typedef unsigned int u32;
typedef unsigned long long u64;

__device__ __forceinline__ u32 umin32(u32 a, u32 b) { return a < b ? a : b; }
__device__ __forceinline__ unsigned short f2bf(float f) {   // fp32 -> bf16 RNE
    unsigned u = __float_as_uint(f);
    return (unsigned short)((u + 0x7fffu + ((u >> 16) & 1u)) >> 16);
}
__device__ __forceinline__ float sigm(float v) { return 1.0f / (1.0f + __expf(-v)); }
__device__ __forceinline__ float tanhv(float v) { float e = __expf(2.0f * v); return 1.0f - 2.0f / (e + 1.0f); }
__device__ __forceinline__ void stw(u32* p, u32 v) {
    __hip_atomic_store(p, v, __ATOMIC_RELAXED, __HIP_MEMORY_SCOPE_AGENT);
}
__device__ __forceinline__ int ld_flag(const int* p) {
    return __hip_atomic_load(p, __ATOMIC_RELAXED, __HIP_MEMORY_SCOPE_AGENT);
}
__device__ __forceinline__ void st_flag(int* p, int v) {
    __hip_atomic_store(p, v, __ATOMIC_RELAXED, __HIP_MEMORY_SCOPE_AGENT);
}
// two tagged u32 words -> one packed dword of 2 bf16 (low halves)
__device__ __forceinline__ bf16x8 mkfrag(f32x4 lo, f32x4 hi) {
    union { u32 w[4]; bf16x8 h; } o;
    o.w[0] = __builtin_amdgcn_perm(__float_as_uint(lo[1]), __float_as_uint(lo[0]), 0x05040100u);
    o.w[1] = __builtin_amdgcn_perm(__float_as_uint(lo[3]), __float_as_uint(lo[2]), 0x05040100u);
    o.w[2] = __builtin_amdgcn_perm(__float_as_uint(hi[1]), __float_as_uint(hi[0]), 0x05040100u);
    o.w[3] = __builtin_amdgcn_perm(__float_as_uint(hi[3]), __float_as_uint(hi[2]), 0x05040100u);
    return o.h;
}
__device__ __forceinline__ bf16x8 cvtfrag(f32x4 a, f32x4 b) {  // fp32x8 -> bf16x8
    bf16x8 h;
    h[0]=(short)f2bf(a[0]); h[1]=(short)f2bf(a[1]); h[2]=(short)f2bf(a[2]); h[3]=(short)f2bf(a[3]);
    h[4]=(short)f2bf(b[0]); h[5]=(short)f2bf(b[1]); h[6]=(short)f2bf(b[2]); h[7]=(short)f2bf(b[3]);
    return h;
}

// 32 x 16B tagged loads for one rowtile (16 rows x 512 feats as u32):
// frag i at imm offsets {i*128, i*128+16}, single base address.
#define GLDC(C, VA)                                                    \
  asm volatile(                                                        \
    "global_load_dwordx4 %0,  %32, off offset:0 sc0 sc1\n\t"          \
    "global_load_dwordx4 %1,  %32, off offset:16 sc0 sc1\n\t"         \
    "global_load_dwordx4 %2,  %32, off offset:128 sc0 sc1\n\t"        \
    "global_load_dwordx4 %3,  %32, off offset:144 sc0 sc1\n\t"        \
    "global_load_dwordx4 %4,  %32, off offset:256 sc0 sc1\n\t"        \
    "global_load_dwordx4 %5,  %32, off offset:272 sc0 sc1\n\t"        \
    "global_load_dwordx4 %6,  %32, off offset:384 sc0 sc1\n\t"        \
    "global_load_dwordx4 %7,  %32, off offset:400 sc0 sc1\n\t"        \
    "global_load_dwordx4 %8,  %32, off offset:512 sc0 sc1\n\t"        \
    "global_load_dwordx4 %9,  %32, off offset:528 sc0 sc1\n\t"        \
    "global_load_dwordx4 %10, %32, off offset:640 sc0 sc1\n\t"        \
    "global_load_dwordx4 %11, %32, off offset:656 sc0 sc1\n\t"        \
    "global_load_dwordx4 %12, %32, off offset:768 sc0 sc1\n\t"        \
    "global_load_dwordx4 %13, %32, off offset:784 sc0 sc1\n\t"        \
    "global_load_dwordx4 %14, %32, off offset:896 sc0 sc1\n\t"        \
    "global_load_dwordx4 %15, %32, off offset:912 sc0 sc1\n\t"        \
    "global_load_dwordx4 %16, %32, off offset:1024 sc0 sc1\n\t"       \
    "global_load_dwordx4 %17, %32, off offset:1040 sc0 sc1\n\t"       \
    "global_load_dwordx4 %18, %32, off offset:1152 sc0 sc1\n\t"       \
    "global_load_dwordx4 %19, %32, off offset:1168 sc0 sc1\n\t"       \
    "global_load_dwordx4 %20, %32, off offset:1280 sc0 sc1\n\t"       \
    "global_load_dwordx4 %21, %32, off offset:1296 sc0 sc1\n\t"       \
    "global_load_dwordx4 %22, %32, off offset:1408 sc0 sc1\n\t"       \
    "global_load_dwordx4 %23, %32, off offset:1424 sc0 sc1\n\t"       \
    "global_load_dwordx4 %24, %32, off offset:1536 sc0 sc1\n\t"       \
    "global_load_dwordx4 %25, %32, off offset:1552 sc0 sc1\n\t"       \
    "global_load_dwordx4 %26, %32, off offset:1664 sc0 sc1\n\t"       \
    "global_load_dwordx4 %27, %32, off offset:1680 sc0 sc1\n\t"       \
    "global_load_dwordx4 %28, %32, off offset:1792 sc0 sc1\n\t"       \
    "global_load_dwordx4 %29, %32, off offset:1808 sc0 sc1\n\t"       \
    "global_load_dwordx4 %30, %32, off offset:1920 sc0 sc1\n\t"       \
    "global_load_dwordx4 %31, %32, off offset:1936 sc0 sc1\n\t"       \
    "s_waitcnt vmcnt(0)"                                               \
    : "=&v"(C[0]), "=&v"(C[1]), "=&v"(C[2]), "=&v"(C[3]),              \
      "=&v"(C[4]), "=&v"(C[5]), "=&v"(C[6]), "=&v"(C[7]),              \
      "=&v"(C[8]), "=&v"(C[9]), "=&v"(C[10]), "=&v"(C[11]),            \
      "=&v"(C[12]), "=&v"(C[13]), "=&v"(C[14]), "=&v"(C[15]),          \
      "=&v"(C[16]), "=&v"(C[17]), "=&v"(C[18]), "=&v"(C[19]),          \
      "=&v"(C[20]), "=&v"(C[21]), "=&v"(C[22]), "=&v"(C[23]),          \
      "=&v"(C[24]), "=&v"(C[25]), "=&v"(C[26]), "=&v"(C[27]),          \
      "=&v"(C[28]), "=&v"(C[29]), "=&v"(C[30]), "=&v"(C[31])           \
    : "v"(VA) : "memory")

// 4B/lane sentinel load (one word per producer block x rowtile)
#define SENTD(VA, TGT) do { u32 s_;                                          \
    for (;;) {                                                               \
      asm volatile("global_load_dword %0, %1, off sc0 sc1\n\t"               \
                   "s_waitcnt vmcnt(0)"                                      \
                   : "=&v"(s_) : "v"(VA) : "memory");                        \
      if (__all((int)(s_ >= (TGT)))) break;                                  \
    } } while (0)

// batched rowtile load + full tag verification (retry until all fresh)
#define CHUNK_SPIN_READ(C, VA, TGT) do {                                     \
    for (;;) {                                                               \
      GLDC(C, VA);                                                           \
      u32 m0_ = 0xffffffffu, m1_ = 0xffffffffu,                              \
          m2_ = 0xffffffffu, m3_ = 0xffffffffu;                              \
      _Pragma("unroll")                                                      \
      for (int i2_ = 0; i2_ < 32; ++i2_) {                                   \
        m0_ = umin32(m0_, __float_as_uint(C[i2_][0]));                       \
        m1_ = umin32(m1_, __float_as_uint(C[i2_][1]));                       \
        m2_ = umin32(m2_, __float_as_uint(C[i2_][2]));                       \
        m3_ = umin32(m3_, __float_as_uint(C[i2_][3]));                       \
      }                                                                      \
      if (__all((int)(umin32(umin32(m0_, m1_), umin32(m2_, m3_)) >= (TGT)))) \
        break;                                                               \
    } } while (0)

#define CHUNK_MFMA(C, ACC, RT, WB)                                           \
    _Pragma("unroll")                                                        \
    for (int i3_ = 0; i3_ < 16; ++i3_) {                                     \
      bf16x8 a_ = mkfrag(C[2 * i3_], C[2 * i3_ + 1]);                        \
      _Pragma("unroll")                                                      \
      for (int q3_ = 0; q3_ < 4; ++q3_)                                      \
        ACC[(RT) * 4 + q3_] = __builtin_amdgcn_mfma_f32_16x16x32_bf16(       \
            a_, WB[i3_ * 4 + q3_], ACC[(RT) * 4 + q3_], 0, 0, 0);            \
    }

__global__ void lstm_prep(u64* __restrict__ z, long n, int* __restrict__ fl) {
    long tid = (long)blockIdx.x * blockDim.x + threadIdx.x;
    if (tid < 256) st_flag(fl + tid, 0);
    long stride = (long)gridDim.x * blockDim.x;
    for (long i = tid; i < n; i += stride)
        __hip_atomic_store(z + i, (u64)0, __ATOMIC_RELAXED, __HIP_MEMORY_SCOPE_AGENT);
}

__launch_bounds__(256, 1)
__global__ void lstm_main(const float* __restrict__ x,
                          const float* __restrict__ wxh0, const float* __restrict__ whh0,
                          const float* __restrict__ wxh1, const float* __restrict__ whh1,
                          const float* __restrict__ bx0, const float* __restrict__ bh0,
                          const float* __restrict__ bx1, const float* __restrict__ bh1,
                          float* __restrict__ out,
                          u32* __restrict__ ring0, u32* __restrict__ ring1,
                          int* __restrict__ flags, int ns0) {
    extern __shared__ char smem[];
    f32x4* pb   = (f32x4*)smem;                         // [PD][2][8][64]
    int* fdone  = (int*)(smem + PD * 2 * 8 * 64 * 16);  // [PD][2]
    int* fcons  = fdone + PD * 2;                       // [PD][2]

    const int layer = blockIdx.x >> 5;
    const int cb    = blockIdx.x & 31;       // cols [cb*16, cb*16+16)
    const int wv    = threadIdx.x >> 6;
    const int lane  = threadIdx.x & 63;
    const int r     = wv & 1;                // rows [r*32, r*32+32)
    const int role  = wv >> 1;               // 0 = feed, 1 = rec
    const int quad  = lane >> 4;
    const int ln    = lane & 15;
    const int colh  = (cb << 4) + ln;

    // ---- weight slice for this wave, fp32 -> bf16, register-resident ----
    const float* Wsrc; int Kd, NI;
    if (role == 0) {
        if (layer == 0) { Wsrc = wxh0; Kd = In; NI = 8;  }
        else            { Wsrc = wxh1; Kd = Hn; NI = 16; }
    } else {
        Wsrc = (layer == 0) ? whh0 : whh1; Kd = Hn; NI = 16;
    }
    bf16x8 wB[64];
#pragma unroll
    for (int i = 0; i < 16; ++i) {
        if (i < NI) {
#pragma unroll
            for (int q = 0; q < 4; ++q) {
                const float* src = Wsrc + (size_t)(q * Hn + colh) * Kd + i * 32 + quad * 8;
                wB[i * 4 + q] = cvtfrag(*(const f32x4*)src, *(const f32x4*)(src + 4));
            }
        }
    }
    float bias[4];
#pragma unroll
    for (int q = 0; q < 4; ++q)
        bias[q] = (layer == 0) ? (bx0[q * Hn + colh] + bh0[q * Hn + colh])
                               : (bx1[q * Hn + colh] + bh1[q * Hn + colh]);

    if (threadIdx.x < PD * 2) { fdone[threadIdx.x] = 0; fcons[threadIdx.x] = 0; }
    __syncthreads();                          // one-time init sync only

    // per-lane chunk/sentinel offsets (u32 ring, byte units)
    const u64 laneoff = (u64)((size_t)((r * 32 + ln) * 512 + quad * 8) * 4);
    const size_t soff = (size_t)((r * 32 + (lane & 15) + ((lane >> 5) << 4)) * 512
                                 + ((lane & 31) << 4));

    if (role == 0 && layer == 0) {
        // ================= FEED L0: x(t) @ Wxh0, free-running =================
        for (int t = 0; t < Tn; ++t) {
            f32x4 acc[8];
#pragma unroll
            for (int k = 0; k < 8; ++k) {
                float b = bias[k & 3];
                acc[k] = (f32x4){b, b, b, b};
            }
#pragma unroll
            for (int rt = 0; rt < 2; ++rt) {
                const float* xp = x + ((size_t)(r * 32 + rt * 16 + ln) * Tn + t) * In + quad * 8;
                f32x4 xa[16];
#pragma unroll
                for (int i = 0; i < 8; ++i) {
                    xa[2 * i]     = *(const f32x4*)(xp + i * 32);
                    xa[2 * i + 1] = *(const f32x4*)(xp + i * 32 + 4);
                }
#pragma unroll
                for (int i = 0; i < 8; ++i) {
                    bf16x8 af = cvtfrag(xa[2 * i], xa[2 * i + 1]);
#pragma unroll
                    for (int q = 0; q < 4; ++q)
                        acc[rt * 4 + q] = __builtin_amdgcn_mfma_f32_16x16x32_bf16(
                            af, wB[i * 4 + q], acc[rt * 4 + q], 0, 0, 0);
                }
            }
            // hand partials to rec wave r (slot t mod PD)
            int p = t & (PD - 1);
            while (__hip_atomic_load(&fcons[p * 2 + r], __ATOMIC_ACQUIRE,
                                     __HIP_MEMORY_SCOPE_WORKGROUP) < t - PD + 1)
                __builtin_amdgcn_s_sleep(1);
#pragma unroll
            for (int k = 0; k < 8; ++k) pb[((p * 2 + r) * 8 + k) * 64 + lane] = acc[k];
            asm volatile("s_waitcnt lgkmcnt(0)" ::: "memory");
            if (lane == 0)
                __hip_atomic_store(&fdone[p * 2 + r], t + 1, __ATOMIC_RELEASE,
                                   __HIP_MEMORY_SCOPE_WORKGROUP);
        }
    } else if (role == 0) {
        // ============ FEED L1: h0(t) @ Wxh1, elastic behind L0 ============
        int fsl = 1;                          // slot of h0(t) = (t+1) % ns0
        for (int t = 0; t < Tn; ++t) {
            const u32 tgt = ((u32)(t + 1)) << 16;
            const u32* sb = ring0 + (size_t)fsl * SLOTU;
            u64 vas = (u64)(uintptr_t)(sb + soff);
            u64 va0 = (u64)(uintptr_t)sb + laneoff;
            u64 va1 = va0 + (u64)(16 * 512 * 4);
            f32x4 acc[8];
#pragma unroll
            for (int k = 0; k < 8; ++k) {
                float b = bias[k & 3];
                acc[k] = (f32x4){b, b, b, b};
            }
            SENTD(vas, tgt);
            f32x4 C[32];
            CHUNK_SPIN_READ(C, va0, tgt);
            CHUNK_MFMA(C, acc, 0, wB);
            CHUNK_SPIN_READ(C, va1, tgt);
            // both rowtiles consumed -> release L0's ring slot
            if (lane == 0) st_flag(flags + cb * 2 + r, t + 1);
            CHUNK_MFMA(C, acc, 1, wB);
            int p = t & (PD - 1);
            while (__hip_atomic_load(&fcons[p * 2 + r], __ATOMIC_ACQUIRE,
                                     __HIP_MEMORY_SCOPE_WORKGROUP) < t - PD + 1)
                __builtin_amdgcn_s_sleep(1);
#pragma unroll
            for (int k = 0; k < 8; ++k) pb[((p * 2 + r) * 8 + k) * 64 + lane] = acc[k];
            asm volatile("s_waitcnt lgkmcnt(0)" ::: "memory");
            if (lane == 0)
                __hip_atomic_store(&fdone[p * 2 + r], t + 1, __ATOMIC_RELEASE,
                                   __HIP_MEMORY_SCOPE_WORKGROUP);
            fsl = (fsl + 1 == ns0) ? 0 : fsl + 1;
        }
    } else {
        // ===== REC: h(t-1) @ Whh (the serial chain) + epilogue + h stores =====
        u32* ringR   = (layer == 0) ? ring0 : ring1;
        const int nsR = (layer == 0) ? ns0 : NS1;
        f32x4 acc[8];
        float cst[8];
#pragma unroll
        for (int k = 0; k < 8; ++k) cst[k] = 0.f;
        int rsl = 0, gseen = 0;
        for (int t = 0; t < Tn; ++t) {
            const u32 tgt = ((u32)t) << 16;    // h(t-1) carries tag t
            const u32* sb = ringR + (size_t)rsl * SLOTU;
            u64 vas = (u64)(uintptr_t)(sb + soff);
            u64 va0 = (u64)(uintptr_t)sb + laneoff;
            u64 va1 = va0 + (u64)(16 * 512 * 4);
#pragma unroll
            for (int k = 0; k < 8; ++k) acc[k] = (f32x4){0.f, 0.f, 0.f, 0.f};
            SENTD(vas, tgt);                   // the pacing spin
            f32x4 C[32];
            CHUNK_SPIN_READ(C, va0, tgt);
            CHUNK_MFMA(C, acc, 0, wB);
            CHUNK_SPIN_READ(C, va1, tgt);
            CHUNK_MFMA(C, acc, 1, wB);
            // fold in feed partial (usually ready)
            int p = t & (PD - 1);
            while (__hip_atomic_load(&fdone[p * 2 + r], __ATOMIC_ACQUIRE,
                                     __HIP_MEMORY_SCOPE_WORKGROUP) < t + 1)
                __builtin_amdgcn_s_sleep(1);
#pragma unroll
            for (int k = 0; k < 8; ++k) acc[k] += pb[((p * 2 + r) * 8 + k) * 64 + lane];
            asm volatile("s_waitcnt lgkmcnt(0)" ::: "memory");
            if (lane == 0)
                __hip_atomic_store(&fcons[p * 2 + r], t + 1, __ATOMIC_RELEASE,
                                   __HIP_MEMORY_SCOPE_WORKGROUP);
            // ring-reuse guard (L0 only): L1 feeds must have consumed h0(t-ns0).
            // Batched: try g+48 first so steady state polls ~once per 48 steps.
            if (layer == 0) {
                int g = t + 1 - ns0;
                if (g > gseen) {
                    const int* gf = flags + lane;
                    int v = ld_flag(gf);
                    if (__all(v >= g + 48)) gseen = g + 48;
                    else {
                        while (!__all(v >= g)) { __builtin_amdgcn_s_sleep(8); v = ld_flag(gf); }
                        gseen = g;
                    }
                }
            }
            // epilogue: 8 rows/lane, tagged fire-and-forget h stores
            int wsl = (rsl + 1 == nsR) ? 0 : rsl + 1;
            u32* wr = ringR + (size_t)wsl * SLOTU;
            const u32 tagb = ((u32)(t + 1)) << 16;
#pragma unroll
            for (int rt = 0; rt < 2; ++rt) {
#pragma unroll
                for (int j = 0; j < 4; ++j) {
                    int row = r * 32 + rt * 16 + quad * 4 + j;
                    float ig = sigm(acc[rt * 4 + 0][j]);
                    float fg = sigm(acc[rt * 4 + 1][j]);
                    float gg = tanhv(acc[rt * 4 + 2][j]);
                    float og = sigm(acc[rt * 4 + 3][j]);
                    float cy = cst[rt * 4 + j] * fg + ig * gg;
                    float hy = og * tanhv(cy);
                    cst[rt * 4 + j] = cy;
                    stw(wr + (size_t)row * 512 + colh, tagb | (u32)f2bf(hy));
                    if (layer == 1) out[(size_t)row * (Tn * Hn) + (size_t)t * Hn + colh] = hy;
                    if (t == Tn - 1) {
                        out[OUT_HT + layer * (Bn * Hn) + row * Hn + colh] = hy;
                        out[OUT_CT + layer * (Bn * Hn) + row * Hn + colh] = cy;
                    }
                }
            }
            rsl = wsl;
        }
    }
}

extern "C" void kernel_launch(void* const* d_in, const int* in_sizes, int n_in,
                              void* d_out, int out_size, void* d_ws, size_t ws_size,
                              hipStream_t stream) {
    const float* x    = (const float*)d_in[0];
    const float* wxh0 = (const float*)d_in[1];
    const float* bxh0 = (const float*)d_in[2];
    const float* whh0 = (const float*)d_in[3];
    const float* bhh0 = (const float*)d_in[4];
    const float* wxh1 = (const float*)d_in[5];
    const float* bxh1 = (const float*)d_in[6];
    const float* whh1 = (const float*)d_in[7];
    const float* bhh1 = (const float*)d_in[8];
    float* out = (float*)d_out;

    char* ws = (char*)d_ws;
    int* flags = (int*)ws;
    long avail = (long)((ws_size - 4096) / ((size_t)SLOTU * 4));
    long ns0_l = avail - NS1;
    int ns0 = (int)(ns0_l < 3 ? 3 : (ns0_l > NS0MAX ? NS0MAX : ns0_l));
    u32* ring0 = (u32*)(ws + 4096);
    u32* ring1 = ring0 + (size_t)ns0 * SLOTU;

    static int lds_attr_set = 0;
    if (!lds_attr_set) {
        hipFuncSetAttribute((const void*)lstm_main,
                            hipFuncAttributeMaxDynamicSharedMemorySize, LDS_BYTES);
        lds_attr_set = 1;
    }

    long zero_n = (long)(ns0 + NS1) * (SLOTU / 2);   // u64 count over both rings
    lstm_prep<<<dim3(256), dim3(256), 0, stream>>>((u64*)ring0, zero_n, flags);

    lstm_main<<<dim3(NBLK), dim3(256), LDS_BYTES, stream>>>(
        x, wxh0, whh0, wxh1, whh1, bxh0, bhh0, bxh1, bhh1,
        out, ring0, ring1, flags, ns0);
}

// Round 3
// 3648.810 us; speedup vs baseline: 1.5184x; 1.3471x over previous
//
#include <hip/hip_runtime.h>
#include <stdint.h>

// Problem constants: B=64, T=512, I=256, H=512, L=2
#define Bn 64
#define Tn 512
#define In 256
#define Hn 512
#define NBLK 64                    // 32 blocks layer0 + 32 blocks layer1
#define OUT_HT 16777216            // B*T*H  (start of hT)
#define OUT_CT 16842752            // OUT_HT + 2*B*H (start of cT)
#define LDS_BYTES 131072           // layer1: 64KB wx1-frags + 64KB wh1-frags
#define SLOT_ELEMS (Bn * Hn)       // 32768 bf16 = 64KB per h slot
#define CNT_BYTES 16384            // int cnt[2][4][512]

// ---------------------------------------------------------------------------
// v4 = v1 skeleton (best-known) with the signaling system replaced.
//  * OLD: per-block flags, polled with 64 scattered 4B loads per wave per
//    iteration, sleepless -> hundreds of GB/s of agent-scope probe traffic
//    contending with the data path (theory: this inflates hop latency).
//  * NEW: monotonic counters cnt[layer][wv][t] (no reuse, no reset). Producer
//    wave: vmcnt drain -> one lane0 atomicAdd. Consumer: poll ONE uniform
//    word until ==32 (single coalesced transaction per poll).
//  * L0 computes its x-part MFMAs BEFORE polling (overlap with the wait).
//  * Ring-reuse guard batched: probe step g+32 first, ~1 poll per 32 steps.
// ---------------------------------------------------------------------------

typedef __attribute__((ext_vector_type(8))) short bf16x8;
typedef __attribute__((ext_vector_type(4))) float f32x4;
typedef unsigned long long u64;

__device__ __forceinline__ unsigned short f2bf(float f) {   // fp32 -> bf16 RNE
    unsigned u = __float_as_uint(f);
    return (unsigned short)((u + 0x7fffu + ((u >> 16) & 1u)) >> 16);
}
__device__ __forceinline__ float sigm(float v) { return 1.0f / (1.0f + __expf(-v)); }
__device__ __forceinline__ float tanhv(float v) { float e = __expf(2.0f * v); return 1.0f - 2.0f / (e + 1.0f); }

// sc0/sc1 accesses: bypass per-XCD L1/L2, coherent at Infinity Cache (L3).
__device__ __forceinline__ void stg_coh(unsigned short* p, unsigned short v) {
    __hip_atomic_store(p, v, __ATOMIC_RELAXED, __HIP_MEMORY_SCOPE_AGENT);
}
__device__ __forceinline__ int ld_cnt(const int* p) {
    return __hip_atomic_load(p, __ATOMIC_RELAXED, __HIP_MEMORY_SCOPE_AGENT);
}
__device__ __forceinline__ void st_flag(int* p, int v) {
    __hip_atomic_store(p, v, __ATOMIC_RELAXED, __HIP_MEMORY_SCOPE_AGENT);
}
__device__ __forceinline__ void wait32(const int* p) {      // uniform-addr poll
    while (ld_cnt(p) < 32) { }
}
__device__ __forceinline__ bf16x8 asbf(f32x4 v) {
    union { f32x4 f; bf16x8 h; } u; u.f = v; return u.h;
}

// Batched sc1 frag loads: all issued back-to-back, ONE waitcnt.
#define GLD16(A, VA)                                                   \
  asm volatile(                                                        \
    "global_load_dwordx4 %0,  %16, off offset:0 sc0 sc1\n\t"          \
    "global_load_dwordx4 %1,  %16, off offset:64 sc0 sc1\n\t"         \
    "global_load_dwordx4 %2,  %16, off offset:128 sc0 sc1\n\t"        \
    "global_load_dwordx4 %3,  %16, off offset:192 sc0 sc1\n\t"        \
    "global_load_dwordx4 %4,  %16, off offset:256 sc0 sc1\n\t"        \
    "global_load_dwordx4 %5,  %16, off offset:320 sc0 sc1\n\t"        \
    "global_load_dwordx4 %6,  %16, off offset:384 sc0 sc1\n\t"        \
    "global_load_dwordx4 %7,  %16, off offset:448 sc0 sc1\n\t"        \
    "global_load_dwordx4 %8,  %16, off offset:512 sc0 sc1\n\t"        \
    "global_load_dwordx4 %9,  %16, off offset:576 sc0 sc1\n\t"        \
    "global_load_dwordx4 %10, %16, off offset:640 sc0 sc1\n\t"        \
    "global_load_dwordx4 %11, %16, off offset:704 sc0 sc1\n\t"        \
    "global_load_dwordx4 %12, %16, off offset:768 sc0 sc1\n\t"        \
    "global_load_dwordx4 %13, %16, off offset:832 sc0 sc1\n\t"        \
    "global_load_dwordx4 %14, %16, off offset:896 sc0 sc1\n\t"        \
    "global_load_dwordx4 %15, %16, off offset:960 sc0 sc1\n\t"        \
    "s_waitcnt vmcnt(0)"                                               \
    : "=&v"(A[0]), "=&v"(A[1]), "=&v"(A[2]), "=&v"(A[3]),              \
      "=&v"(A[4]), "=&v"(A[5]), "=&v"(A[6]), "=&v"(A[7]),              \
      "=&v"(A[8]), "=&v"(A[9]), "=&v"(A[10]), "=&v"(A[11]),            \
      "=&v"(A[12]), "=&v"(A[13]), "=&v"(A[14]), "=&v"(A[15])           \
    : "v"(VA) : "memory")

#define GLD32(A, B, VA, VB)                                            \
  asm volatile(                                                        \
    "global_load_dwordx4 %0,  %32, off offset:0 sc0 sc1\n\t"          \
    "global_load_dwordx4 %1,  %32, off offset:64 sc0 sc1\n\t"         \
    "global_load_dwordx4 %2,  %32, off offset:128 sc0 sc1\n\t"        \
    "global_load_dwordx4 %3,  %32, off offset:192 sc0 sc1\n\t"        \
    "global_load_dwordx4 %4,  %32, off offset:256 sc0 sc1\n\t"        \
    "global_load_dwordx4 %5,  %32, off offset:320 sc0 sc1\n\t"        \
    "global_load_dwordx4 %6,  %32, off offset:384 sc0 sc1\n\t"        \
    "global_load_dwordx4 %7,  %32, off offset:448 sc0 sc1\n\t"        \
    "global_load_dwordx4 %8,  %32, off offset:512 sc0 sc1\n\t"        \
    "global_load_dwordx4 %9,  %32, off offset:576 sc0 sc1\n\t"        \
    "global_load_dwordx4 %10, %32, off offset:640 sc0 sc1\n\t"        \
    "global_load_dwordx4 %11, %32, off offset:704 sc0 sc1\n\t"        \
    "global_load_dwordx4 %12, %32, off offset:768 sc0 sc1\n\t"        \
    "global_load_dwordx4 %13, %32, off offset:832 sc0 sc1\n\t"        \
    "global_load_dwordx4 %14, %32, off offset:896 sc0 sc1\n\t"        \
    "global_load_dwordx4 %15, %32, off offset:960 sc0 sc1\n\t"        \
    "global_load_dwordx4 %16, %33, off offset:0 sc0 sc1\n\t"          \
    "global_load_dwordx4 %17, %33, off offset:64 sc0 sc1\n\t"         \
    "global_load_dwordx4 %18, %33, off offset:128 sc0 sc1\n\t"        \
    "global_load_dwordx4 %19, %33, off offset:192 sc0 sc1\n\t"        \
    "global_load_dwordx4 %20, %33, off offset:256 sc0 sc1\n\t"        \
    "global_load_dwordx4 %21, %33, off offset:320 sc0 sc1\n\t"        \
    "global_load_dwordx4 %22, %33, off offset:384 sc0 sc1\n\t"        \
    "global_load_dwordx4 %23, %33, off offset:448 sc0 sc1\n\t"        \
    "global_load_dwordx4 %24, %33, off offset:512 sc0 sc1\n\t"        \
    "global_load_dwordx4 %25, %33, off offset:576 sc0 sc1\n\t"        \
    "global_load_dwordx4 %26, %33, off offset:640 sc0 sc1\n\t"        \
    "global_load_dwordx4 %27, %33, off offset:704 sc0 sc1\n\t"        \
    "global_load_dwordx4 %28, %33, off offset:768 sc0 sc1\n\t"        \
    "global_load_dwordx4 %29, %33, off offset:832 sc0 sc1\n\t"        \
    "global_load_dwordx4 %30, %33, off offset:896 sc0 sc1\n\t"        \
    "global_load_dwordx4 %31, %33, off offset:960 sc0 sc1\n\t"        \
    "s_waitcnt vmcnt(0)"                                               \
    : "=&v"(A[0]), "=&v"(A[1]), "=&v"(A[2]), "=&v"(A[3]),              \
      "=&v"(A[4]), "=&v"(A[5]), "=&v"(A[6]), "=&v"(A[7]),              \
      "=&v"(A[8]), "=&v"(A[9]), "=&v"(A[10]), "=&v"(A[11]),            \
      "=&v"(A[12]), "=&v"(A[13]), "=&v"(A[14]), "=&v"(A[15]),          \
      "=&v"(B[0]), "=&v"(B[1]), "=&v"(B[2]), "=&v"(B[3]),              \
      "=&v"(B[4]), "=&v"(B[5]), "=&v"(B[6]), "=&v"(B[7]),              \
      "=&v"(B[8]), "=&v"(B[9]), "=&v"(B[10]), "=&v"(B[11]),            \
      "=&v"(B[12]), "=&v"(B[13]), "=&v"(B[14]), "=&v"(B[15])           \
    : "v"(VA), "v"(VB) : "memory")

__global__ void lstm_prep(u64* __restrict__ z0, u64* __restrict__ z1,
                          int* __restrict__ cnt) {
    int tid = blockIdx.x * blockDim.x + threadIdx.x;
    if (tid < CNT_BYTES / 4) st_flag(cnt + tid, 0);
    for (int i = tid; i < SLOT_ELEMS / 4; i += gridDim.x * blockDim.x) {
        __hip_atomic_store(z0 + i, (u64)0, __ATOMIC_RELAXED, __HIP_MEMORY_SCOPE_AGENT);
        __hip_atomic_store(z1 + i, (u64)0, __ATOMIC_RELAXED, __HIP_MEMORY_SCOPE_AGENT);
    }
}

__launch_bounds__(256, 1)
__global__ void lstm_main(const float* __restrict__ x,
                          const float* __restrict__ wxh0, const float* __restrict__ whh0,
                          const float* __restrict__ wxh1, const float* __restrict__ whh1,
                          const float* __restrict__ bx0, const float* __restrict__ bh0,
                          const float* __restrict__ bx1, const float* __restrict__ bh1,
                          float* __restrict__ out,
                          unsigned short* __restrict__ h0b,
                          unsigned short* __restrict__ h1b,
                          int* __restrict__ cnt, int nslot) {
    extern __shared__ char smem[];
    const int layer = blockIdx.x >> 5;        // 0 or 1
    const int cb    = blockIdx.x & 31;        // owns h cols [cb*16, cb*16+16)
    const int wv    = threadIdx.x >> 6;       // wave -> row tile [16*wv, 16*wv+16)
    const int lane  = threadIdx.x & 63;
    const int quad  = lane >> 4;
    const int ln    = lane & 15;
    const int row0  = wv << 4;
    const int colh  = (cb << 4) + ln;

    // ---- stage weight slices into LDS (fp32 -> bf16 during staging) ----
    const int I0 = (layer == 0) ? 8 : 16;     // x-side K/32
    const int K0 = (layer == 0) ? In : Hn;
    const float* Wxs = (layer == 0) ? wxh0 : wxh1;
    const float* Whs = (layer == 0) ? whh0 : whh1;
    u64* sm64 = (u64*)smem;
    const int tot0 = I0 * 4 * 64;
    for (int c = threadIdx.x; c < tot0; c += 256) {
        int lc = c & 63, qg = (c >> 6) & 3, ii = c >> 8;
        const float* src = Wxs + (size_t)(qg * Hn + (cb << 4) + (lc & 15)) * K0
                               + ii * 32 + (lc >> 4) * 8;
        f32x4 s0 = *(const f32x4*)src;
        f32x4 s1 = *(const f32x4*)(src + 4);
        u64 lo = (u64)f2bf(s0[0]) | ((u64)f2bf(s0[1]) << 16) |
                 ((u64)f2bf(s0[2]) << 32) | ((u64)f2bf(s0[3]) << 48);
        u64 hi = (u64)f2bf(s1[0]) | ((u64)f2bf(s1[1]) << 16) |
                 ((u64)f2bf(s1[2]) << 32) | ((u64)f2bf(s1[3]) << 48);
        sm64[c * 2] = lo; sm64[c * 2 + 1] = hi;
    }
    const int hbase = tot0;
    for (int c = threadIdx.x; c < 16 * 4 * 64; c += 256) {
        int lc = c & 63, qg = (c >> 6) & 3, ii = c >> 8;
        const float* src = Whs + (size_t)(qg * Hn + (cb << 4) + (lc & 15)) * Hn
                               + ii * 32 + (lc >> 4) * 8;
        f32x4 s0 = *(const f32x4*)src;
        f32x4 s1 = *(const f32x4*)(src + 4);
        u64 lo = (u64)f2bf(s0[0]) | ((u64)f2bf(s0[1]) << 16) |
                 ((u64)f2bf(s0[2]) << 32) | ((u64)f2bf(s0[3]) << 48);
        u64 hi = (u64)f2bf(s1[0]) | ((u64)f2bf(s1[1]) << 16) |
                 ((u64)f2bf(s1[2]) << 32) | ((u64)f2bf(s1[3]) << 48);
        sm64[(hbase + c) * 2] = lo; sm64[(hbase + c) * 2 + 1] = hi;
    }
    __syncthreads();                          // the ONLY block-wide sync
    const bf16x8* bfr = (const bf16x8*)smem;

    float bias[4];
#pragma unroll
    for (int q = 0; q < 4; ++q) {
        int gc = q * Hn + colh;
        bias[q] = (layer == 0) ? (bx0[gc] + bh0[gc]) : (bx1[gc] + bh1[gc]);
    }

    const float* xrow0 = x + (size_t)(row0 + ln) * Tn * In + quad * 8;
    const int hoff = (row0 + ln) * Hn + quad * 8;   // *2B -> 16B aligned

    // counter topology: cnt[layer][wv][t] at cnt[(layer*4+wv)*Tn + t].
    // Producer wave (layer,cb,wv): after drain, lane0 atomicAdd(+1) at step t.
    // Rows align across blocks: consumer wave wv only needs producer waves wv.
    const int* c0 = cnt + (0 * 4 + wv) * Tn;  // layer0 rowtile wv counters
    const int* c1 = cnt + (1 * 4 + wv) * Tn;  // layer1 rowtile wv counters
    int* pub = cnt + (layer * 4 + wv) * Tn;

    float c[4] = {0.f, 0.f, 0.f, 0.f};
    int rs = 0, wsl = 1;                      // slots: h(t-1) at rs, h(t) at wsl
    int gdone = -1;                           // ring guard: L1 steps known done

    for (int t = 0; t < Tn; ++t) {
        f32x4 acc[4];
#pragma unroll
        for (int q = 0; q < 4; ++q) acc[q] = (f32x4){bias[q], bias[q], bias[q], bias[q]};

        if (layer == 0) {
            // ---- x-part first: no dependence -> overlaps the h wait ----
            const float* xp = xrow0 + (size_t)t * In;
            f32x4 xr[16];
#pragma unroll
            for (int i = 0; i < 8; ++i) {
                xr[2 * i]     = *(const f32x4*)(xp + i * 32);
                xr[2 * i + 1] = *(const f32x4*)(xp + i * 32 + 4);
            }
            bf16x8 axc[8];
#pragma unroll
            for (int i = 0; i < 8; ++i) {
                f32x4 xa = xr[2 * i], xc = xr[2 * i + 1];
                axc[i][0] = (short)f2bf(xa[0]); axc[i][1] = (short)f2bf(xa[1]);
                axc[i][2] = (short)f2bf(xa[2]); axc[i][3] = (short)f2bf(xa[3]);
                axc[i][4] = (short)f2bf(xc[0]); axc[i][5] = (short)f2bf(xc[1]);
                axc[i][6] = (short)f2bf(xc[2]); axc[i][7] = (short)f2bf(xc[3]);
            }
#pragma unroll
            for (int i = 0; i < 8; ++i)
#pragma unroll
                for (int q = 0; q < 4; ++q)
                    acc[q] = __builtin_amdgcn_mfma_f32_16x16x32_bf16(
                        axc[i], bfr[(i * 4 + q) * 64 + lane], acc[q], 0, 0, 0);

            // ---- wait for h0(t-1) rows [row0,row0+16) from all 32 blocks ----
            if (t > 0) wait32(c0 + (t - 1));
            // ---- ring-reuse guard: L1 must have consumed h0(t+1-nslot). ----
            // Batched: probe step g+32 first -> ~1 poll per 32 steps.
            {
                int g = t + 1 - nslot;
                if (g >= 0 && g > gdone) {
                    int probe = g + 32; if (probe > Tn - 1) probe = Tn - 1;
                    if (ld_cnt(c1 + probe) >= 32) gdone = probe;
                    else { wait32(c1 + g); gdone = g; }
                }
            }
            asm volatile("" ::: "memory");    // no load hoisting above the spin

            const unsigned short* hp = h0b + (size_t)rs * SLOT_ELEMS + hoff;
            f32x4 A[16];
            uint64_t va = (uint64_t)hp;
            GLD16(A, va);
#pragma unroll
            for (int i = 0; i < 16; ++i)
#pragma unroll
                for (int q = 0; q < 4; ++q)
                    acc[q] = __builtin_amdgcn_mfma_f32_16x16x32_bf16(
                        asbf(A[i]), bfr[hbase + (i * 4 + q) * 64 + lane], acc[q], 0, 0, 0);
        } else {
            // ---- L1: wait for h0(t) and h1(t-1), then one batched load ----
            wait32(c0 + t);
            if (t > 0) wait32(c1 + (t - 1));
            asm volatile("" ::: "memory");

            const unsigned short* p0 = h0b + (size_t)wsl * SLOT_ELEMS + hoff;  // h0(t)
            const unsigned short* p1 = h1b + (size_t)rs  * SLOT_ELEMS + hoff;  // h1(t-1)
            f32x4 A[16], Bv[16];
            uint64_t va = (uint64_t)p0, vb = (uint64_t)p1;
            GLD32(A, Bv, va, vb);
#pragma unroll
            for (int i = 0; i < 16; ++i)
#pragma unroll
                for (int q = 0; q < 4; ++q)
                    acc[q] = __builtin_amdgcn_mfma_f32_16x16x32_bf16(
                        asbf(A[i]), bfr[(i * 4 + q) * 64 + lane], acc[q], 0, 0, 0);
#pragma unroll
            for (int i = 0; i < 16; ++i)
#pragma unroll
                for (int q = 0; q < 4; ++q)
                    acc[q] = __builtin_amdgcn_mfma_f32_16x16x32_bf16(
                        asbf(Bv[i]), bfr[hbase + (i * 4 + q) * 64 + lane], acc[q], 0, 0, 0);
        }

        // ---- LSTM cell epilogue; sc1 h stores (L3-coherent) ----
        unsigned short* hw = ((layer == 0) ? h0b : h1b) + (size_t)wsl * SLOT_ELEMS;
#pragma unroll
        for (int r = 0; r < 4; ++r) {
            int row = row0 + quad * 4 + r;
            float ig = sigm(acc[0][r]);
            float fg = sigm(acc[1][r]);
            float gg = tanhv(acc[2][r]);
            float og = sigm(acc[3][r]);
            float cy = c[r] * fg + ig * gg;
            float hy = og * tanhv(cy);
            c[r] = cy;
            stg_coh(hw + row * Hn + colh, f2bf(hy));
            if (layer == 1) out[(size_t)row * (Tn * Hn) + (size_t)t * Hn + colh] = hy;
            if (t == Tn - 1) {
                out[OUT_HT + layer * (Bn * Hn) + row * Hn + colh] = hy;
                out[OUT_CT + layer * (Bn * Hn) + row * Hn + colh] = cy;
            }
        }

        // publish: own stores at L3 (vmcnt drain), then one atomicAdd per wave
        asm volatile("s_waitcnt vmcnt(0)" ::: "memory");
        if (lane == 0)
            __hip_atomic_fetch_add(pub + t, 1, __ATOMIC_RELAXED, __HIP_MEMORY_SCOPE_AGENT);

        rs = wsl;
        wsl = (wsl + 1 == nslot) ? 0 : wsl + 1;
    }
}

extern "C" void kernel_launch(void* const* d_in, const int* in_sizes, int n_in,
                              void* d_out, int out_size, void* d_ws, size_t ws_size,
                              hipStream_t stream) {
    const float* x    = (const float*)d_in[0];
    const float* wxh0 = (const float*)d_in[1];
    const float* bxh0 = (const float*)d_in[2];
    const float* whh0 = (const float*)d_in[3];
    const float* bhh0 = (const float*)d_in[4];
    const float* wxh1 = (const float*)d_in[5];
    const float* bxh1 = (const float*)d_in[6];
    const float* whh1 = (const float*)d_in[7];
    const float* bhh1 = (const float*)d_in[8];
    float* out = (float*)d_out;

    char* ws = (char*)d_ws;
    int* cnt = (int*)ws;
    long nslot_l = (long)((ws_size - CNT_BYTES) / (2 * (size_t)SLOT_ELEMS * 2));
    int nslot = (int)(nslot_l < 3 ? 3 : (nslot_l > Tn + 1 ? Tn + 1 : nslot_l));
    unsigned short* h0b = (unsigned short*)(ws + CNT_BYTES);
    unsigned short* h1b = h0b + (size_t)nslot * SLOT_ELEMS;

    static int lds_attr_set = 0;
    if (!lds_attr_set) {
        hipFuncSetAttribute((const void*)lstm_main,
                            hipFuncAttributeMaxDynamicSharedMemorySize, LDS_BYTES);
        lds_attr_set = 1;
    }

    lstm_prep<<<dim3(32), dim3(256), 0, stream>>>((u64*)h0b, (u64*)h1b, cnt);

    lstm_main<<<dim3(NBLK), dim3(256), LDS_BYTES, stream>>>(
        x, wxh0, whh0, wxh1, whh1, bxh0, bhh0, bxh1, bhh1,
        out, h0b, h1b, cnt, nslot);
}

// Round 5
// 3365.302 us; speedup vs baseline: 1.6463x; 1.0842x over previous
//
#include <hip/hip_runtime.h>
#include <stdint.h>

// Problem constants: B=64, T=512, I=256, H=512, L=2
#define Bn 64
#define Tn 512
#define In 256
#define Hn 512
#define NBLK 64                    // 32 blocks layer0 + 32 blocks layer1
#define OUT_HT 16777216            // B*T*H  (start of hT)
#define OUT_CT 16842752            // OUT_HT + 2*B*H (start of cT)
#define LDS_BYTES 131072           // layer1: 64KB wx1-frags + 64KB wh1-frags
#define SLOT_ELEMS (Bn * Hn)       // 32768 bf16 = 64KB per h slot
#define DONE_WORDS (2 * 4 * Tn * 32)   // done[layer][wv][t][cb] : 512KB
#define DONE_BYTES (DONE_WORDS * 4)

// ---------------------------------------------------------------------------
// v5 (re-run; previous attempt died to container infra, audit found no
// hang/fault path) = v4 skeleton with the serial L3 chain shortened:
//  * done-vector: per-(chain,t) 128B line of 32 plain stores replaces the
//    32-way atomicAdd RMW; detection = one coalesced 32-lane load + __all.
//  * L1: GLD(h0(t)) issued BEFORE the c1(t-1) spin (c0 check is usually
//    instant) -> h0 load latency hides under the binding recurrence wait
//    (the spin's implicit vmcnt(0) drains it for free).
//  * counted vmcnt quarters: issue 16 loads, then vmcnt(N) + sched_barrier(0)
//    before each 4-frag MFMA group (load tail overlaps MFMA).
//  * out/hT/cT stores moved AFTER publish: their HBM acks leave the
//    pre-publish drain (which gates every other block's detect).
// ---------------------------------------------------------------------------

typedef __attribute__((ext_vector_type(8))) short bf16x8;
typedef __attribute__((ext_vector_type(4))) float f32x4;
typedef unsigned long long u64;

__device__ __forceinline__ unsigned short f2bf(float f) {   // fp32 -> bf16 RNE
    unsigned u = __float_as_uint(f);
    return (unsigned short)((u + 0x7fffu + ((u >> 16) & 1u)) >> 16);
}
__device__ __forceinline__ float sigm(float v) { return 1.0f / (1.0f + __expf(-v)); }
__device__ __forceinline__ float tanhv(float v) { float e = __expf(2.0f * v); return 1.0f - 2.0f / (e + 1.0f); }

// sc0/sc1 accesses: bypass per-XCD L1/L2, coherent at Infinity Cache (L3).
__device__ __forceinline__ void stg_coh(unsigned short* p, unsigned short v) {
    __hip_atomic_store(p, v, __ATOMIC_RELAXED, __HIP_MEMORY_SCOPE_AGENT);
}
__device__ __forceinline__ int ld_cnt(const int* p) {
    return __hip_atomic_load(p, __ATOMIC_RELAXED, __HIP_MEMORY_SCOPE_AGENT);
}
__device__ __forceinline__ void st_flag(int* p, int v) {
    __hip_atomic_store(p, v, __ATOMIC_RELAXED, __HIP_MEMORY_SCOPE_AGENT);
}
__device__ __forceinline__ bf16x8 asbf(f32x4 v) {
    union { f32x4 f; bf16x8 h; } u; u.f = v; return u.h;
}

// Issue 16 batched sc1 frag loads, NO trailing waitcnt (counted waits follow).
#define GLD16_ISSUE(A, VA)                                             \
  asm volatile(                                                        \
    "global_load_dwordx4 %0,  %16, off offset:0 sc0 sc1\n\t"          \
    "global_load_dwordx4 %1,  %16, off offset:64 sc0 sc1\n\t"         \
    "global_load_dwordx4 %2,  %16, off offset:128 sc0 sc1\n\t"        \
    "global_load_dwordx4 %3,  %16, off offset:192 sc0 sc1\n\t"        \
    "global_load_dwordx4 %4,  %16, off offset:256 sc0 sc1\n\t"        \
    "global_load_dwordx4 %5,  %16, off offset:320 sc0 sc1\n\t"        \
    "global_load_dwordx4 %6,  %16, off offset:384 sc0 sc1\n\t"        \
    "global_load_dwordx4 %7,  %16, off offset:448 sc0 sc1\n\t"        \
    "global_load_dwordx4 %8,  %16, off offset:512 sc0 sc1\n\t"        \
    "global_load_dwordx4 %9,  %16, off offset:576 sc0 sc1\n\t"        \
    "global_load_dwordx4 %10, %16, off offset:640 sc0 sc1\n\t"        \
    "global_load_dwordx4 %11, %16, off offset:704 sc0 sc1\n\t"        \
    "global_load_dwordx4 %12, %16, off offset:768 sc0 sc1\n\t"        \
    "global_load_dwordx4 %13, %16, off offset:832 sc0 sc1\n\t"        \
    "global_load_dwordx4 %14, %16, off offset:896 sc0 sc1\n\t"        \
    "global_load_dwordx4 %15, %16, off offset:960 sc0 sc1"             \
    : "=&v"(A[0]), "=&v"(A[1]), "=&v"(A[2]), "=&v"(A[3]),              \
      "=&v"(A[4]), "=&v"(A[5]), "=&v"(A[6]), "=&v"(A[7]),              \
      "=&v"(A[8]), "=&v"(A[9]), "=&v"(A[10]), "=&v"(A[11]),            \
      "=&v"(A[12]), "=&v"(A[13]), "=&v"(A[14]), "=&v"(A[15])           \
    : "v"(VA) : "memory")

// Counted wait + scheduling fence (rule #18: MFMA can hoist past asm waits).
#define VMW(n) do {                                                    \
    asm volatile("s_waitcnt vmcnt(" #n ")" ::: "memory");              \
    __builtin_amdgcn_sched_barrier(0);                                 \
  } while (0)

__global__ void lstm_prep(u64* __restrict__ z0, u64* __restrict__ z1,
                          int* __restrict__ dn) {
    int tid = blockIdx.x * blockDim.x + threadIdx.x;      // 65536 threads
    int stride = gridDim.x * blockDim.x;
    for (int i = tid; i < DONE_WORDS; i += stride) st_flag(dn + i, 0);
    for (int i = tid; i < SLOT_ELEMS / 4; i += stride) {
        __hip_atomic_store(z0 + i, (u64)0, __ATOMIC_RELAXED, __HIP_MEMORY_SCOPE_AGENT);
        __hip_atomic_store(z1 + i, (u64)0, __ATOMIC_RELAXED, __HIP_MEMORY_SCOPE_AGENT);
    }
}

__launch_bounds__(256, 1)
__global__ void lstm_main(const float* __restrict__ x,
                          const float* __restrict__ wxh0, const float* __restrict__ whh0,
                          const float* __restrict__ wxh1, const float* __restrict__ whh1,
                          const float* __restrict__ bx0, const float* __restrict__ bh0,
                          const float* __restrict__ bx1, const float* __restrict__ bh1,
                          float* __restrict__ out,
                          unsigned short* __restrict__ h0b,
                          unsigned short* __restrict__ h1b,
                          int* __restrict__ done, int nslot) {
    extern __shared__ char smem[];
    const int layer = blockIdx.x >> 5;        // 0 or 1
    const int cb    = blockIdx.x & 31;        // owns h cols [cb*16, cb*16+16)
    const int wv    = threadIdx.x >> 6;       // wave -> row tile [16*wv, 16*wv+16)
    const int lane  = threadIdx.x & 63;
    const int quad  = lane >> 4;
    const int ln    = lane & 15;
    const int row0  = wv << 4;
    const int colh  = (cb << 4) + ln;

    // ---- stage weight slices into LDS (fp32 -> bf16 during staging) ----
    const int I0 = (layer == 0) ? 8 : 16;     // x-side K/32
    const int K0 = (layer == 0) ? In : Hn;
    const float* Wxs = (layer == 0) ? wxh0 : wxh1;
    const float* Whs = (layer == 0) ? whh0 : whh1;
    u64* sm64 = (u64*)smem;
    const int tot0 = I0 * 4 * 64;
    for (int c = threadIdx.x; c < tot0; c += 256) {
        int lc = c & 63, qg = (c >> 6) & 3, ii = c >> 8;
        const float* src = Wxs + (size_t)(qg * Hn + (cb << 4) + (lc & 15)) * K0
                               + ii * 32 + (lc >> 4) * 8;
        f32x4 s0 = *(const f32x4*)src;
        f32x4 s1 = *(const f32x4*)(src + 4);
        u64 lo = (u64)f2bf(s0[0]) | ((u64)f2bf(s0[1]) << 16) |
                 ((u64)f2bf(s0[2]) << 32) | ((u64)f2bf(s0[3]) << 48);
        u64 hi = (u64)f2bf(s1[0]) | ((u64)f2bf(s1[1]) << 16) |
                 ((u64)f2bf(s1[2]) << 32) | ((u64)f2bf(s1[3]) << 48);
        sm64[c * 2] = lo; sm64[c * 2 + 1] = hi;
    }
    const int hbase = tot0;
    for (int c = threadIdx.x; c < 16 * 4 * 64; c += 256) {
        int lc = c & 63, qg = (c >> 6) & 3, ii = c >> 8;
        const float* src = Whs + (size_t)(qg * Hn + (cb << 4) + (lc & 15)) * Hn
                               + ii * 32 + (lc >> 4) * 8;
        f32x4 s0 = *(const f32x4*)src;
        f32x4 s1 = *(const f32x4*)(src + 4);
        u64 lo = (u64)f2bf(s0[0]) | ((u64)f2bf(s0[1]) << 16) |
                 ((u64)f2bf(s0[2]) << 32) | ((u64)f2bf(s0[3]) << 48);
        u64 hi = (u64)f2bf(s1[0]) | ((u64)f2bf(s1[1]) << 16) |
                 ((u64)f2bf(s1[2]) << 32) | ((u64)f2bf(s1[3]) << 48);
        sm64[(hbase + c) * 2] = lo; sm64[(hbase + c) * 2 + 1] = hi;
    }
    __syncthreads();                          // the ONLY block-wide sync
    const bf16x8* bfr = (const bf16x8*)smem;

    float bias[4];
#pragma unroll
    for (int q = 0; q < 4; ++q) {
        int gc = q * Hn + colh;
        bias[q] = (layer == 0) ? (bx0[gc] + bh0[gc]) : (bx1[gc] + bh1[gc]);
    }

    const float* xrow0 = x + (size_t)(row0 + ln) * Tn * In + quad * 8;
    const int hoff = (row0 + ln) * Hn + quad * 8;   // *2B -> 16B aligned

    // done topology: done[(layer*4+wv)*Tn + t][cb].  Producer wave: after
    // h-store drain, lane0 plain-stores t+1.  Consumer: 32-lane coalesced
    // load of the line (lanes 32..63 mirror 0..31) + __all(v > 0).
    const int lm = lane & 31;
    const int* d0 = done + ((0 * 4 + wv) * Tn) * 32 + lm;  // + t*32
    const int* d1 = done + ((1 * 4 + wv) * Tn) * 32 + lm;
    int* pub = done + ((layer * 4 + wv) * Tn) * 32 + cb;   // + t*32

    float c[4] = {0.f, 0.f, 0.f, 0.f};
    int rs = 0, wsl = 1;                      // slots: h(t-1) at rs, h(t) at wsl
    int gdone = -1;                           // ring guard: L1 steps known done

    for (int t = 0; t < Tn; ++t) {
        f32x4 acc[4];
#pragma unroll
        for (int q = 0; q < 4; ++q) acc[q] = (f32x4){bias[q], bias[q], bias[q], bias[q]};

        if (layer == 0) {
            // ---- x-part first: no dependence -> overlaps the h wait ----
            const float* xp = xrow0 + (size_t)t * In;
            f32x4 xr[16];
#pragma unroll
            for (int i = 0; i < 8; ++i) {
                xr[2 * i]     = *(const f32x4*)(xp + i * 32);
                xr[2 * i + 1] = *(const f32x4*)(xp + i * 32 + 4);
            }
            bf16x8 axc[8];
#pragma unroll
            for (int i = 0; i < 8; ++i) {
                f32x4 xa = xr[2 * i], xc = xr[2 * i + 1];
                axc[i][0] = (short)f2bf(xa[0]); axc[i][1] = (short)f2bf(xa[1]);
                axc[i][2] = (short)f2bf(xa[2]); axc[i][3] = (short)f2bf(xa[3]);
                axc[i][4] = (short)f2bf(xc[0]); axc[i][5] = (short)f2bf(xc[1]);
                axc[i][6] = (short)f2bf(xc[2]); axc[i][7] = (short)f2bf(xc[3]);
            }
#pragma unroll
            for (int i = 0; i < 8; ++i)
#pragma unroll
                for (int q = 0; q < 4; ++q)
                    acc[q] = __builtin_amdgcn_mfma_f32_16x16x32_bf16(
                        axc[i], bfr[(i * 4 + q) * 64 + lane], acc[q], 0, 0, 0);

            // ---- ring-reuse guard: L1 must have consumed h0(t+1-nslot). ----
            // Batched (probe g+32 first) and rare -> s_sleep backoff is safe.
            {
                int g = t + 1 - nslot;
                if (g >= 0 && g > gdone) {
                    int probe = g + 32; if (probe > Tn - 1) probe = Tn - 1;
                    if (__all(ld_cnt(d1 + probe * 32) > 0)) gdone = probe;
                    else {
                        const int* gp = d1 + g * 32;
                        while (!__all(ld_cnt(gp) > 0)) __builtin_amdgcn_s_sleep(4);
                        gdone = g;
                    }
                }
            }
            // ---- wait for h0(t-1) rows [row0,row0+16) from all 32 blocks ----
            if (t > 0) {
                const int* p = d0 + (t - 1) * 32;
                while (!__all(ld_cnt(p) > 0)) { }
            }
            asm volatile("" ::: "memory");    // no load hoisting above the spin

            const unsigned short* hp = h0b + (size_t)rs * SLOT_ELEMS + hoff;
            f32x4 A[16];
            uint64_t va = (uint64_t)hp;
            GLD16_ISSUE(A, va);
            VMW(12);
#pragma unroll
            for (int i = 0; i < 4; ++i)
#pragma unroll
                for (int q = 0; q < 4; ++q)
                    acc[q] = __builtin_amdgcn_mfma_f32_16x16x32_bf16(
                        asbf(A[i]), bfr[hbase + (i * 4 + q) * 64 + lane], acc[q], 0, 0, 0);
            VMW(8);
#pragma unroll
            for (int i = 4; i < 8; ++i)
#pragma unroll
                for (int q = 0; q < 4; ++q)
                    acc[q] = __builtin_amdgcn_mfma_f32_16x16x32_bf16(
                        asbf(A[i]), bfr[hbase + (i * 4 + q) * 64 + lane], acc[q], 0, 0, 0);
            VMW(4);
#pragma unroll
            for (int i = 8; i < 12; ++i)
#pragma unroll
                for (int q = 0; q < 4; ++q)
                    acc[q] = __builtin_amdgcn_mfma_f32_16x16x32_bf16(
                        asbf(A[i]), bfr[hbase + (i * 4 + q) * 64 + lane], acc[q], 0, 0, 0);
            VMW(0);
#pragma unroll
            for (int i = 12; i < 16; ++i)
#pragma unroll
                for (int q = 0; q < 4; ++q)
                    acc[q] = __builtin_amdgcn_mfma_f32_16x16x32_bf16(
                        asbf(A[i]), bfr[hbase + (i * 4 + q) * 64 + lane], acc[q], 0, 0, 0);
        } else {
            // ---- L1: c0 check (usually instant), issue h0 loads, THEN the
            //      binding c1 spin (its polls drain h0 in-flight), then h1 ----
            {
                const int* p = d0 + t * 32;
                while (!__all(ld_cnt(p) > 0)) { }
            }
            asm volatile("" ::: "memory");
            const unsigned short* p0 = h0b + (size_t)wsl * SLOT_ELEMS + hoff;  // h0(t)
            f32x4 A[16], Bv[16];
            uint64_t va = (uint64_t)p0;
            GLD16_ISSUE(A, va);
            if (t > 0) {
                const int* p = d1 + (t - 1) * 32;
                while (!__all(ld_cnt(p) > 0)) { }
            }
            asm volatile("" ::: "memory");
            const unsigned short* p1 = h1b + (size_t)rs * SLOT_ELEMS + hoff;   // h1(t-1)
            uint64_t vb = (uint64_t)p1;
            GLD16_ISSUE(Bv, vb);
            // h0 quarters: waits pass instantly when the c1 spin drained A.
            VMW(28);
#pragma unroll
            for (int i = 0; i < 4; ++i)
#pragma unroll
                for (int q = 0; q < 4; ++q)
                    acc[q] = __builtin_amdgcn_mfma_f32_16x16x32_bf16(
                        asbf(A[i]), bfr[(i * 4 + q) * 64 + lane], acc[q], 0, 0, 0);
            VMW(24);
#pragma unroll
            for (int i = 4; i < 8; ++i)
#pragma unroll
                for (int q = 0; q < 4; ++q)
                    acc[q] = __builtin_amdgcn_mfma_f32_16x16x32_bf16(
                        asbf(A[i]), bfr[(i * 4 + q) * 64 + lane], acc[q], 0, 0, 0);
            VMW(20);
#pragma unroll
            for (int i = 8; i < 12; ++i)
#pragma unroll
                for (int q = 0; q < 4; ++q)
                    acc[q] = __builtin_amdgcn_mfma_f32_16x16x32_bf16(
                        asbf(A[i]), bfr[(i * 4 + q) * 64 + lane], acc[q], 0, 0, 0);
            VMW(16);
#pragma unroll
            for (int i = 12; i < 16; ++i)
#pragma unroll
                for (int q = 0; q < 4; ++q)
                    acc[q] = __builtin_amdgcn_mfma_f32_16x16x32_bf16(
                        asbf(A[i]), bfr[(i * 4 + q) * 64 + lane], acc[q], 0, 0, 0);
            VMW(12);
#pragma unroll
            for (int i = 0; i < 4; ++i)
#pragma unroll
                for (int q = 0; q < 4; ++q)
                    acc[q] = __builtin_amdgcn_mfma_f32_16x16x32_bf16(
                        asbf(Bv[i]), bfr[hbase + (i * 4 + q) * 64 + lane], acc[q], 0, 0, 0);
            VMW(8);
#pragma unroll
            for (int i = 4; i < 8; ++i)
#pragma unroll
                for (int q = 0; q < 4; ++q)
                    acc[q] = __builtin_amdgcn_mfma_f32_16x16x32_bf16(
                        asbf(Bv[i]), bfr[hbase + (i * 4 + q) * 64 + lane], acc[q], 0, 0, 0);
            VMW(4);
#pragma unroll
            for (int i = 8; i < 12; ++i)
#pragma unroll
                for (int q = 0; q < 4; ++q)
                    acc[q] = __builtin_amdgcn_mfma_f32_16x16x32_bf16(
                        asbf(Bv[i]), bfr[hbase + (i * 4 + q) * 64 + lane], acc[q], 0, 0, 0);
            VMW(0);
#pragma unroll
            for (int i = 12; i < 16; ++i)
#pragma unroll
                for (int q = 0; q < 4; ++q)
                    acc[q] = __builtin_amdgcn_mfma_f32_16x16x32_bf16(
                        asbf(Bv[i]), bfr[hbase + (i * 4 + q) * 64 + lane], acc[q], 0, 0, 0);
        }

        // ---- LSTM cell epilogue; h-stores -> drain -> publish -> out ----
        unsigned short* hw = ((layer == 0) ? h0b : h1b) + (size_t)wsl * SLOT_ELEMS;
        float hv[4];
#pragma unroll
        for (int r = 0; r < 4; ++r) {
            int row = row0 + quad * 4 + r;
            float ig = sigm(acc[0][r]);
            float fg = sigm(acc[1][r]);
            float gg = tanhv(acc[2][r]);
            float og = sigm(acc[3][r]);
            float cy = c[r] * fg + ig * gg;
            float hy = og * tanhv(cy);
            c[r] = cy;
            hv[r] = hy;
            stg_coh(hw + row * Hn + colh, f2bf(hy));
        }
        asm volatile("s_waitcnt vmcnt(0)" ::: "memory");
        if (lane == 0) st_flag(pub + t * 32, t + 1);

        // out / hT / cT: off the publish path (acks overlap next-step waits)
        if (layer == 1) {
#pragma unroll
            for (int r = 0; r < 4; ++r) {
                int row = row0 + quad * 4 + r;
                out[(size_t)row * (Tn * Hn) + (size_t)t * Hn + colh] = hv[r];
            }
        }
        if (t == Tn - 1) {
#pragma unroll
            for (int r = 0; r < 4; ++r) {
                int row = row0 + quad * 4 + r;
                out[OUT_HT + layer * (Bn * Hn) + row * Hn + colh] = hv[r];
                out[OUT_CT + layer * (Bn * Hn) + row * Hn + colh] = c[r];
            }
        }

        rs = wsl;
        wsl = (wsl + 1 == nslot) ? 0 : wsl + 1;
    }
}

extern "C" void kernel_launch(void* const* d_in, const int* in_sizes, int n_in,
                              void* d_out, int out_size, void* d_ws, size_t ws_size,
                              hipStream_t stream) {
    const float* x    = (const float*)d_in[0];
    const float* wxh0 = (const float*)d_in[1];
    const float* bxh0 = (const float*)d_in[2];
    const float* whh0 = (const float*)d_in[3];
    const float* bhh0 = (const float*)d_in[4];
    const float* wxh1 = (const float*)d_in[5];
    const float* bxh1 = (const float*)d_in[6];
    const float* whh1 = (const float*)d_in[7];
    const float* bhh1 = (const float*)d_in[8];
    float* out = (float*)d_out;

    char* ws = (char*)d_ws;
    int* done = (int*)ws;
    long nslot_l = (long)((ws_size - DONE_BYTES) / (2 * (size_t)SLOT_ELEMS * 2));
    int nslot = (int)(nslot_l < 3 ? 3 : (nslot_l > Tn + 1 ? Tn + 1 : nslot_l));
    unsigned short* h0b = (unsigned short*)(ws + DONE_BYTES);
    unsigned short* h1b = h0b + (size_t)nslot * SLOT_ELEMS;

    static int lds_attr_set = 0;
    if (!lds_attr_set) {
        hipFuncSetAttribute((const void*)lstm_main,
                            hipFuncAttributeMaxDynamicSharedMemorySize, LDS_BYTES);
        lds_attr_set = 1;
    }

    lstm_prep<<<dim3(256), dim3(256), 0, stream>>>((u64*)h0b, (u64*)h1b, done);

    lstm_main<<<dim3(NBLK), dim3(256), LDS_BYTES, stream>>>(
        x, wxh0, whh0, wxh1, whh1, bxh0, bhh0, bxh1, bhh1,
        out, h0b, h1b, done, nslot);
}